// Round 1
// 323.661 us; speedup vs baseline: 1.0583x; 1.0583x over previous
//
#include <hip/hip_runtime.h>
#include <hip/hip_bf16.h>
#include <math.h>

typedef __hip_bfloat16 hbf16;
typedef __attribute__((ext_vector_type(8))) __bf16    bf16x8;
typedef __attribute__((ext_vector_type(4))) float     f32x4;
typedef __attribute__((ext_vector_type(4))) _Float16  f16x4;
typedef __attribute__((ext_vector_type(8))) unsigned short u16x8;

#define C_    1024
#define NTOK  256
#define NH    16
#define J3    3072

__device__ __forceinline__ unsigned short fbits(float v){
    return __builtin_bit_cast(unsigned short, __float2bfloat16(v));
}
__device__ __forceinline__ __bf16 to_bf(float v){
    return __builtin_bit_cast(__bf16, __float2bfloat16(v));
}

__device__ __forceinline__ void gload_lds16(const __bf16* g, __bf16* l) {
    __builtin_amdgcn_global_load_lds((const __attribute__((address_space(1))) void*)g,
                                     (__attribute__((address_space(3))) void*)l, 16, 0, 0);
}

// ---------------------------------------------------------------------------
// cvt both weight tensors in one launch. blocks [0,3072) -> w_qkv, rest -> w_lin
// ---------------------------------------------------------------------------
__global__ __launch_bounds__(256) void cvt_w(const float* __restrict__ wq,
                                             __bf16* __restrict__ wqo,
                                             const float* __restrict__ wl,
                                             __bf16* __restrict__ wlo) {
    const float* in; __bf16* out; int i;
    if (blockIdx.x < 3072) { in = wq; out = wqo; i = blockIdx.x * 256 + threadIdx.x; }
    else                   { in = wl; out = wlo; i = (blockIdx.x - 3072) * 256 + threadIdx.x; }
    float4 v = ((const float4*)in)[i];
    ushort4 u;
    u.x = fbits(v.x); u.y = fbits(v.y); u.z = fbits(v.z); u.w = fbits(v.w);
    ((ushort4*)out)[i] = u;
}

// ---------------------------------------------------------------------------
// xpose_x: X[64,1024,256] f32 -> Xt[b*256+s][k] bf16   (32x32 LDS tiles)
// ---------------------------------------------------------------------------
__global__ __launch_bounds__(256) void xpose_x(const float* __restrict__ X,
                                               __bf16* __restrict__ Xt) {
    __shared__ float t[32][36];
    const int b = blockIdx.z, k0 = blockIdx.y * 32, s0 = blockIdx.x * 32;
    const int tid = threadIdx.x;
    {
        int kl = tid >> 3, s4 = (tid & 7) * 4;
        float4 v = *(const float4*)(X + ((size_t)b << 18) + (size_t)(k0 + kl) * 256 + s0 + s4);
        t[kl][s4] = v.x; t[kl][s4 + 1] = v.y; t[kl][s4 + 2] = v.z; t[kl][s4 + 3] = v.w;
    }
    __syncthreads();
    {
        int sl = tid >> 3, k4 = (tid & 7) * 4;
        ushort4 u;
        u.x = fbits(t[k4][sl]); u.y = fbits(t[k4 + 1][sl]);
        u.z = fbits(t[k4 + 2][sl]); u.w = fbits(t[k4 + 3][sl]);
        *(ushort4*)(Xt + (size_t)(b * 256 + s0 + sl) * 1024 + k0 + k4) = u;
    }
}

// ---------------------------------------------------------------------------
// gemm256: C[m,n] = sum_k A[m,k]*B[n,k], A[16384,1024], B[3072,1024] bf16,
// C -> bf16 row-major ldc=3072.
// 256x256 tile, BK=32, TRIPLE-buffered LDS (96 KiB), 8 waves (2Mx4N),
// counted vmcnt (steady-state vmcnt(4), never 0 until the last tile),
// one raw s_barrier per K-tile, XOR-swizzled LDS (2-way = free),
// setprio(1) around the 32-MFMA cluster, bijective XCD block swizzle.
//
// Pipeline: after barrier of iter t, issue stage of tile t+2 into buf (t+2)%3.
//   - buf (t+2)%3's previous tenant (tile t-1) finished its reads before this
//     barrier (program order), so the issue is safe.
//   - wait at iter t: outstanding = tiles {t, t+1} = 8 loads; vmcnt(4) drains
//     exactly tile t's 4 (vmcnt retires in issue order); barrier makes all
//     waves' tile-t loads visible.
// ---------------------------------------------------------------------------
#define WAITVM(N) asm volatile("s_waitcnt vmcnt(" #N ")" ::: "memory")

__device__ __forceinline__ void stage_tile(const __bf16* __restrict__ Ag,
                                           const __bf16* __restrict__ Bg,
                                           __bf16* sa, __bf16* sb,
                                           int kk, int wave, int lane) {
    // wave-load = 64 lanes x 16B = 1 KiB = 16 rows of 64B. Linear LDS dest;
    // the read-side swizzle (chunk ^= (row>>1)&3) is pre-applied to the
    // per-lane GLOBAL source chunk: cg = (lane&3) ^ ((lane>>3)&3).
    const int rl = lane >> 2;
    const int cg = (lane & 3) ^ ((lane >> 3) & 3);
    const int coff = kk + cg * 8;
    #pragma unroll
    for (int i = 0; i < 2; ++i) {
        const int seg = wave * 2 + i;            // 0..15 -> rows seg*16..+16
        const int row = seg * 16 + rl;
        gload_lds16(Ag + ((size_t)row << 10) + coff, sa + seg * 512);
        gload_lds16(Bg + ((size_t)row << 10) + coff, sb + seg * 512);
    }
}

__global__ __launch_bounds__(512, 2) void gemm256(const __bf16* __restrict__ A,
                                                  const __bf16* __restrict__ B,
                                                  __bf16* __restrict__ Y) {
    __shared__ union __align__(16) {
        struct { __bf16 A[3 * 8192]; __bf16 B[3 * 8192]; } kl;   // 96 KiB
        __bf16 st[128][264];                                      // 66 KiB epi
    } sm;

    const int tid  = threadIdx.x;
    const int wave = tid >> 6, lane = tid & 63;
    const int wm = wave >> 2, wn = wave & 3;        // 2 x 4 wave grid
    const int quad = lane >> 4, m = lane & 15;

    // bijective XCD swizzle: 768 blocks = 8 xcd x (8 mb x 12 nb)
    const int wg = blockIdx.x;
    const int local = wg >> 3;                       // 0..95
    const int mb = (wg & 7) * 8 + (local & 7);       // 0..63
    const int nb = local >> 3;                       // 0..11
    const int m0 = mb << 8, n0 = nb << 8;

    const __bf16* Ab = A + ((size_t)m0 << 10);
    const __bf16* Bb = B + ((size_t)n0 << 10);

    // per-thread constant fragment offsets (elements).
    // swizzle: phys_chunk = quad ^ ((row>>1)&3); row base mult of 16 =>
    // ((row>>1)&3) == ((lane>>1)&3) for row = base + (lane&15).
    const int pcs  = quad ^ ((lane >> 1) & 3);
    const int aoff = (wm * 128 + m) * 32 + pcs * 8;  // + mi*512
    const int boff = (wn * 64  + m) * 32 + pcs * 8;  // + ni*512

    f32x4 acc[8][4] = {};

    // prologue: tiles 0,1 -> bufs 0,1
    stage_tile(Ab, Bb, sm.kl.A,         sm.kl.B,         0,  wave, lane);
    stage_tile(Ab, Bb, sm.kl.A + 8192,  sm.kl.B + 8192,  32, wave, lane);

    int bt = 0, b2 = 2;
    for (int t = 0; t < 32; ++t) {
        if (t < 31) { WAITVM(4); } else { WAITVM(0); }
        __builtin_amdgcn_sched_barrier(0);
        __builtin_amdgcn_s_barrier();
        __builtin_amdgcn_sched_barrier(0);

        if (t < 30)
            stage_tile(Ab, Bb, sm.kl.A + b2 * 8192, sm.kl.B + b2 * 8192,
                       (t + 2) << 5, wave, lane);

        const __bf16* sa = sm.kl.A + bt * 8192 + aoff;
        const __bf16* sb = sm.kl.B + bt * 8192 + boff;
        bf16x8 bfr[4], afr[8];
        #pragma unroll
        for (int ni = 0; ni < 4; ++ni) bfr[ni] = *(const bf16x8*)(sb + ni * 512);
        #pragma unroll
        for (int mi = 0; mi < 8; ++mi) afr[mi] = *(const bf16x8*)(sa + mi * 512);

        __builtin_amdgcn_s_setprio(1);
        #pragma unroll
        for (int mi = 0; mi < 8; ++mi)
            #pragma unroll
            for (int ni = 0; ni < 4; ++ni)
                acc[mi][ni] = __builtin_amdgcn_mfma_f32_16x16x32_bf16(
                    afr[mi], bfr[ni], acc[mi][ni], 0, 0, 0);
        __builtin_amdgcn_s_setprio(0);

        bt = (bt == 2) ? 0 : bt + 1;
        b2 = (b2 == 2) ? 0 : b2 + 1;
    }

    // ---- epilogue: stage 128-row halves through LDS, coalesced bf16x8 stores
    __syncthreads();
    #pragma unroll
    for (int h = 0; h < 2; ++h) {
        if (wm == h) {
            #pragma unroll
            for (int mi = 0; mi < 8; ++mi)
                #pragma unroll
                for (int ni = 0; ni < 4; ++ni) {
                    const int r = mi * 16 + quad * 4;
                    const int c = wn * 64 + ni * 16 + m;
                    #pragma unroll
                    for (int j = 0; j < 4; ++j)
                        sm.st[r + j][c] = to_bf(acc[mi][ni][j]);
                }
        }
        __syncthreads();
        #pragma unroll
        for (int i = 0; i < 8; ++i) {
            const int cid = i * 512 + tid;
            const int r = cid >> 5, ch = (cid & 31) * 8;
            *(bf16x8*)(Y + (size_t)(m0 + h * 128 + r) * 3072 + n0 + ch) =
                *(const bf16x8*)&sm.st[r][ch];
        }
        __syncthreads();
    }
}

// ---------------------------------------------------------------------------
// mfma_gemm<EPI=1>: A=Wl (m=oc), B=Ot (n=b*256+s): direct stores
// out[b][oc][s] = C + bias[oc].  (128x128 tile, BK=64, 4 waves.)
// ---------------------------------------------------------------------------
template <int EPI>
__global__ __launch_bounds__(256) void mfma_gemm(const __bf16* __restrict__ A,
                                                 const __bf16* __restrict__ B,
                                                 void* __restrict__ Cout,
                                                 const float* __restrict__ bias) {
    __shared__ union __align__(16) {
        struct { __bf16 A[128 * 64]; __bf16 B[128 * 64]; } kl;
        __bf16 stY[128][136];
    } sm;

    const int tid  = threadIdx.x;
    const int wave = tid >> 6, lane = tid & 63;
    const int wm = wave & 1, wn = wave >> 1;
    const int m0 = blockIdx.x * 128, n0 = blockIdx.y * 128;

    const int srow = lane >> 3;
    const int lchunk = (lane & 7) ^ srow;

    f32x4 acc[4][4] = {};

    for (int kk = 0; kk < 1024; kk += 64) {
        #pragma unroll
        for (int g4 = 0; g4 < 4; ++g4) {
            const int g = g4 * 4 + wave;
            const int row = g * 8 + srow;
            gload_lds16(A + (((size_t)(m0 + row)) << 10) + kk + lchunk * 8,
                        &sm.kl.A[g * 512]);
            gload_lds16(B + (((size_t)(n0 + row)) << 10) + kk + lchunk * 8,
                        &sm.kl.B[g * 512]);
        }
        __syncthreads();

        #pragma unroll
        for (int t = 0; t < 2; ++t) {
            const int chunk = t * 4 + (lane >> 4);
            bf16x8 af[4], bf[4];
            #pragma unroll
            for (int mi = 0; mi < 4; ++mi) {
                int row = wm * 64 + mi * 16 + (lane & 15);
                af[mi] = *(const bf16x8*)&sm.kl.A[row * 64 + ((chunk ^ (row & 7)) << 3)];
            }
            #pragma unroll
            for (int ni = 0; ni < 4; ++ni) {
                int row = wn * 64 + ni * 16 + (lane & 15);
                bf[ni] = *(const bf16x8*)&sm.kl.B[row * 64 + ((chunk ^ (row & 7)) << 3)];
            }
            #pragma unroll
            for (int mi = 0; mi < 4; ++mi)
                #pragma unroll
                for (int ni = 0; ni < 4; ++ni)
                    acc[mi][ni] = __builtin_amdgcn_mfma_f32_16x16x32_bf16(
                        af[mi], bf[ni], acc[mi][ni], 0, 0, 0);
        }
        __syncthreads();
    }

    const int cl = lane & 15, rq = lane >> 4;

    if (EPI == 0) {
        __syncthreads();
        #pragma unroll
        for (int mi = 0; mi < 4; ++mi)
            #pragma unroll
            for (int ni = 0; ni < 4; ++ni) {
                int row = wm * 64 + mi * 16 + rq * 4;
                int col = wn * 64 + ni * 16 + cl;
                #pragma unroll
                for (int j = 0; j < 4; ++j)
                    sm.stY[row + j][col] = to_bf(acc[mi][ni][j]);
            }
        __syncthreads();
        __bf16* Y = (__bf16*)Cout;
        #pragma unroll
        for (int i = 0; i < 8; ++i) {
            int cid = tid + 256 * i;
            int r = cid >> 4, c8 = (cid & 15) * 8;
            *(bf16x8*)(Y + (size_t)(m0 + r) * 3072 + n0 + c8) =
                *(const bf16x8*)&sm.stY[r][c8];
        }
    } else {
        float* out = (float*)Cout;
        float bia[4][4];
        const int rbase = m0 + wm * 64 + rq * 4;
        #pragma unroll
        for (int mi = 0; mi < 4; ++mi)
            #pragma unroll
            for (int j = 0; j < 4; ++j) bia[mi][j] = bias[rbase + mi * 16 + j];
        const int nbase = n0 + wn * 64 + cl;
        #pragma unroll
        for (int mi = 0; mi < 4; ++mi)
            #pragma unroll
            for (int ni = 0; ni < 4; ++ni) {
                int nn = nbase + ni * 16;
                size_t base = ((size_t)(nn >> 8) << 18) + (nn & 255);
                #pragma unroll
                for (int j = 0; j < 4; ++j) {
                    int oc = rbase + mi * 16 + j;
                    out[base + ((size_t)oc << 8)] = acc[mi][ni][j] + bia[mi][j];
                }
            }
    }
}

// ---------------------------------------------------------------------------
// attn_mfma: 16 waves/block, one token per wave (16 consecutive n of one batch).
// o = (softmax_d(rope(q))*scale · softmax_h(rope(k))^T) · v   via MFMA.
// ---------------------------------------------------------------------------
__global__ __launch_bounds__(1024) void attn_mfma(const __bf16* __restrict__ Y,
                                                  __bf16* __restrict__ Ot) {
    __shared__ union __align__(16) {
        __bf16  v[16][1024];      // per-wave v[16 h][64 e]
        ushort4 ost[256][16];     // [s][slot] row-strips (XOR-swizzled slots)
    } sm;

    const int tid  = threadIdx.x;
    const int wave = tid >> 6, lane = tid & 63;
    const int bb = blockIdx.x >> 4;
    const int n0 = (blockIdx.x & 15) * 16;
    const int n  = n0 + wave;
    const int quad = lane >> 4, m = lane & 15;
    const __bf16* Yt = Y + (size_t)(bb * 256 + n) * J3;

    #pragma unroll
    for (int p = 0; p < 2; ++p) {
        const int h = p * 8 + (lane >> 3), part = lane & 7;
        gload_lds16(Yt + h * 192 + 128 + part * 8, &sm.v[wave][p * 512]);
    }

    bf16x8 qb[2], kb[2];
    #pragma unroll
    for (int st = 0; st < 2; ++st) {
        qb[st] = *(const bf16x8*)(Yt + m * 192 +      st * 32 + quad * 8);
        kb[st] = *(const bf16x8*)(Yt + m * 192 + 64 + st * 32 + quad * 8);
    }
    float qf[16], kf[16];
    #pragma unroll
    for (int st = 0; st < 2; ++st)
        #pragma unroll
        for (int j = 0; j < 8; ++j) {
            qf[st * 8 + j] = (float)qb[st][j];
            kf[st * 8 + j] = (float)kb[st][j];
        }

    const float fn = (float)n;
    #pragma unroll
    for (int j = 0; j < 8; ++j) {
        const float d  = (float)(quad * 8 + j);
        const float th = fn * __expf(-0.28782313662425572f * d);  // n * 10000^(-d/32)
        const float sn = __sinf(th), cn = __cosf(th);
        float a0 = qf[j], a1 = qf[8 + j];
        qf[j]     = a0 * cn - a1 * sn;
        qf[8 + j] = a1 * cn + a0 * sn;
        float b0 = kf[j], b1 = kf[8 + j];
        kf[j]     = b0 * cn - b1 * sn;
        kf[8 + j] = b1 * cn + b0 * sn;
    }

    float qe[16], ls = 0.f;
    #pragma unroll
    for (int i = 0; i < 16; ++i) { qe[i] = __expf(qf[i]); ls += qe[i]; }
    ls += __shfl_xor(ls, 16);
    ls += __shfl_xor(ls, 32);
    const float qinv = 0.125f * __builtin_amdgcn_rcpf(ls);
    bf16x8 qbh[2];
    #pragma unroll
    for (int st = 0; st < 2; ++st)
        #pragma unroll
        for (int j = 0; j < 8; ++j) qbh[st][j] = to_bf(qe[st * 8 + j] * qinv);

    float ke[16], kc[16];
    #pragma unroll
    for (int i = 0; i < 16; ++i) { ke[i] = __expf(kf[i]); kc[i] = ke[i]; }
    #pragma unroll
    for (int msk = 1; msk <= 8; msk <<= 1)
        #pragma unroll
        for (int i = 0; i < 16; ++i) kc[i] += __shfl_xor(kc[i], msk);
    bf16x8 kbh[2];
    #pragma unroll
    for (int st = 0; st < 2; ++st)
        #pragma unroll
        for (int j = 0; j < 8; ++j)
            kbh[st][j] = to_bf(ke[st * 8 + j] * __builtin_amdgcn_rcpf(kc[st * 8 + j]));

    f32x4 Sp = {0.f, 0.f, 0.f, 0.f};
    Sp = __builtin_amdgcn_mfma_f32_16x16x32_bf16(kbh[0], qbh[0], Sp, 0, 0, 0);
    Sp = __builtin_amdgcn_mfma_f32_16x16x32_bf16(kbh[1], qbh[1], Sp, 0, 0, 0);

    __syncthreads();   // drain v DMA before LDS picks

    f32x4 o4[4];
#if __has_builtin(__builtin_amdgcn_mfma_f32_16x16x16f16)
    f16x4 af;
    #pragma unroll
    for (int r = 0; r < 4; ++r) af[r] = (_Float16)Sp[r];
    #pragma unroll
    for (int tile = 0; tile < 4; ++tile) {
        f16x4 bv;
        #pragma unroll
        for (int j = 0; j < 4; ++j)
            bv[j] = (_Float16)(float)sm.v[wave][(quad * 4 + j) * 64 + tile * 16 + m];
        f32x4 z = {0.f, 0.f, 0.f, 0.f};
        o4[tile] = __builtin_amdgcn_mfma_f32_16x16x16f16(af, bv, z, 0, 0, 0);
    }
#else
    bf16x8 a2;
    #pragma unroll
    for (int j = 0; j < 8; ++j) {
        int k = quad * 8 + j;
        int src = ((k & 15) >> 2) * 16 + m;
        float v = __shfl(Sp[k & 3], src, 64);
        a2[j] = (quad < 2) ? to_bf(v) : to_bf(0.f);
    }
    #pragma unroll
    for (int tile = 0; tile < 4; ++tile) {
        bf16x8 bv;
        #pragma unroll
        for (int j = 0; j < 8; ++j) {
            int k = quad * 8 + j;
            int kk = (k < 16) ? k : 0;
            bv[j] = sm.v[wave][kk * 64 + tile * 16 + m];
        }
        f32x4 z = {0.f, 0.f, 0.f, 0.f};
        o4[tile] = __builtin_amdgcn_mfma_f32_16x16x32_bf16(a2, bv, z, 0, 0, 0);
    }
#endif

    __syncthreads();   // v dead; reuse LDS as ost

    #pragma unroll
    for (int r = 0; r < 4; ++r) {
        const int s = m * 16 + quad * 4 + r;
        const int phys = wave ^ (quad * 4 + r) ^ m;
        ushort4 u;
        u.x = fbits(o4[0][r]); u.y = fbits(o4[1][r]);
        u.z = fbits(o4[2][r]); u.w = fbits(o4[3][r]);
        sm.ost[s][phys] = u;
    }
    __syncthreads();

    {
        const int row = tid >> 2;
        const int w0  = (tid & 3) * 4;
        ushort4 u4[4];
        #pragma unroll
        for (int j = 0; j < 4; ++j) {
            const int phys = (w0 + j) ^ (row & 15) ^ (row >> 4);
            u4[j] = sm.ost[row][phys];
        }
        __bf16* dst = Ot + (((size_t)(bb * 256 + row)) << 10) + n0 * 4 + w0 * 4;
        u16x8 a = {u4[0].x, u4[0].y, u4[0].z, u4[0].w, u4[1].x, u4[1].y, u4[1].z, u4[1].w};
        u16x8 b = {u4[2].x, u4[2].y, u4[2].z, u4[2].w, u4[3].x, u4[3].y, u4[3].z, u4[3].w};
        *(u16x8*)dst = a;
        *(u16x8*)(dst + 8) = b;
    }
}

// ---------------------------------------------------------------------------
extern "C" void kernel_launch(void* const* d_in, const int* in_sizes, int n_in,
                              void* d_out, int out_size, void* d_ws, size_t ws_size,
                              hipStream_t stream) {
    const float* x     = (const float*)d_in[0];
    const float* w_qkv = (const float*)d_in[1];
    const float* w_lin = (const float*)d_in[2];
    const float* b_lin = (const float*)d_in[3];
    float* out = (float*)d_out;

    char* ws = (char*)d_ws;
    __bf16* Y    = (__bf16*)ws;                               // 96 MiB [16384,3072]
    __bf16* XtOt = (__bf16*)(ws + (size_t)100663296);         // 32 MiB [16384,1024] (Xt then Ot)
    __bf16* Wqb  = (__bf16*)(ws + (size_t)134217728);         // 6 MiB  [3072,1024]
    __bf16* Wlb  = (__bf16*)(ws + (size_t)140509184);         // 2 MiB  [1024,1024]

    cvt_w<<<4096, 256, 0, stream>>>(w_qkv, Wqb, w_lin, Wlb);
    xpose_x<<<dim3(8, 32, 64), 256, 0, stream>>>(x, XtOt);

    gemm256<<<768, 512, 0, stream>>>(XtOt, Wqb, Y);
    attn_mfma<<<1024, 1024, 0, stream>>>(Y, XtOt);            // Xt dead; reuse as Ot
    mfma_gemm<1><<<dim3(8, 128), 256, 0, stream>>>(Wlb, XtOt, (void*)out, b_lin);
}

// Round 2
// 311.551 us; speedup vs baseline: 1.0994x; 1.0389x over previous
//
#include <hip/hip_runtime.h>
#include <hip/hip_bf16.h>
#include <math.h>

typedef __hip_bfloat16 hbf16;
typedef __attribute__((ext_vector_type(8))) __bf16    bf16x8;
typedef __attribute__((ext_vector_type(4))) float     f32x4;
typedef __attribute__((ext_vector_type(4))) _Float16  f16x4;
typedef __attribute__((ext_vector_type(8))) unsigned short u16x8;

#define C_    1024
#define NTOK  256
#define NH    16
#define J3    3072

__device__ __forceinline__ unsigned short fbits(float v){
    return __builtin_bit_cast(unsigned short, __float2bfloat16(v));
}
__device__ __forceinline__ __bf16 to_bf(float v){
    return __builtin_bit_cast(__bf16, __float2bfloat16(v));
}

__device__ __forceinline__ void gload_lds16(const __bf16* g, __bf16* l) {
    __builtin_amdgcn_global_load_lds((const __attribute__((address_space(1))) void*)g,
                                     (__attribute__((address_space(3))) void*)l, 16, 0, 0);
}

// ---------------------------------------------------------------------------
// cvt both weight tensors in one launch. blocks [0,3072) -> w_qkv, rest -> w_lin
// ---------------------------------------------------------------------------
__global__ __launch_bounds__(256) void cvt_w(const float* __restrict__ wq,
                                             __bf16* __restrict__ wqo,
                                             const float* __restrict__ wl,
                                             __bf16* __restrict__ wlo) {
    const float* in; __bf16* out; int i;
    if (blockIdx.x < 3072) { in = wq; out = wqo; i = blockIdx.x * 256 + threadIdx.x; }
    else                   { in = wl; out = wlo; i = (blockIdx.x - 3072) * 256 + threadIdx.x; }
    float4 v = ((const float4*)in)[i];
    ushort4 u;
    u.x = fbits(v.x); u.y = fbits(v.y); u.z = fbits(v.z); u.w = fbits(v.w);
    ((ushort4*)out)[i] = u;
}

// ---------------------------------------------------------------------------
// xpose_x: X[64,1024,256] f32 -> Xt[b*256+s][k] bf16   (32x32 LDS tiles)
// ---------------------------------------------------------------------------
__global__ __launch_bounds__(256) void xpose_x(const float* __restrict__ X,
                                               __bf16* __restrict__ Xt) {
    __shared__ float t[32][36];
    const int b = blockIdx.z, k0 = blockIdx.y * 32, s0 = blockIdx.x * 32;
    const int tid = threadIdx.x;
    {
        int kl = tid >> 3, s4 = (tid & 7) * 4;
        float4 v = *(const float4*)(X + ((size_t)b << 18) + (size_t)(k0 + kl) * 256 + s0 + s4);
        t[kl][s4] = v.x; t[kl][s4 + 1] = v.y; t[kl][s4 + 2] = v.z; t[kl][s4 + 3] = v.w;
    }
    __syncthreads();
    {
        int sl = tid >> 3, k4 = (tid & 7) * 4;
        ushort4 u;
        u.x = fbits(t[k4][sl]); u.y = fbits(t[k4 + 1][sl]);
        u.z = fbits(t[k4 + 2][sl]); u.w = fbits(t[k4 + 3][sl]);
        *(ushort4*)(Xt + (size_t)(b * 256 + s0 + sl) * 1024 + k0 + k4) = u;
    }
}

// ---------------------------------------------------------------------------
// gemm256<EPI>: C[m,n] = sum_k A[m,k]*B[n,k] (both k-contiguous bf16, K=1024)
// 256x256 tile, BK=32, TRIPLE-buffered LDS (96 KiB), 8 waves (2Mx4N),
// register-pipelined fragments: per tile, MFMA half0 consumes frags read
// LAST iteration; this iteration's ds_reads (own half1 + next tile's
// half0+B) stream underneath the 32-MFMA burst (compiler emits counted
// lgkmcnt, never a full drain). Staging via counted vmcnt: stage(t+2)
// issued at iter t, drained at iter t+1 (one full tile of slack).
// EPI=0: C -> bf16 row-major ldc=3072 (Y), LDS-transposed coalesced stores.
// EPI=1: A=Wl (m=oc), B=Ot (n=b*256+s): direct f32 stores out[b][oc][s]+bias.
// ---------------------------------------------------------------------------
#define WAITVM(N) asm volatile("s_waitcnt vmcnt(" #N ")" ::: "memory")

__device__ __forceinline__ void stage_tile(const __bf16* __restrict__ Ag,
                                           const __bf16* __restrict__ Bg,
                                           __bf16* sa, __bf16* sb,
                                           int kk, int wave, int lane) {
    // wave-load = 64 lanes x 16B = 1 KiB = 16 rows of 64B. Linear LDS dest;
    // the read-side swizzle (chunk ^= (row>>1)&3) is pre-applied to the
    // per-lane GLOBAL source chunk: cg = (lane&3) ^ ((lane>>3)&3).
    const int rl = lane >> 2;
    const int cg = (lane & 3) ^ ((lane >> 3) & 3);
    const int coff = kk + cg * 8;
    #pragma unroll
    for (int i = 0; i < 2; ++i) {
        const int seg = wave * 2 + i;            // 0..15 -> rows seg*16..+16
        const int row = seg * 16 + rl;
        gload_lds16(Ag + ((size_t)row << 10) + coff, sa + seg * 512);
        gload_lds16(Bg + ((size_t)row << 10) + coff, sb + seg * 512);
    }
}

// One K-tile. CA/CB: current tile's A-half0 + B frags (read last iteration).
// h1: current tile's A-half1, read HERE. NA/NB: next tile's prefetch.
#define GBODY(BT, NBUF, T, DOSTG, DOPF, CA, CB, NA, NB)                        \
  {                                                                            \
    asm volatile("s_waitcnt vmcnt(0)" ::: "memory");                           \
    __builtin_amdgcn_s_barrier();                                              \
    __builtin_amdgcn_sched_barrier(0);                                         \
    if (DOSTG) stage_tile(Ab, Bb, sm.kl.A + (((BT) + 2) % 3) * 8192,           \
                          sm.kl.B + (((BT) + 2) % 3) * 8192, ((T) + 2) << 5,   \
                          wave, lane);                                         \
    bf16x8 h1[4];                                                              \
    {                                                                          \
      const __bf16* sa_ = sm.kl.A + (BT) * 8192 + aoff;                        \
      _Pragma("unroll") for (int mi = 0; mi < 4; ++mi)                         \
          h1[mi] = *(const bf16x8*)(sa_ + (mi + 4) * 512);                     \
    }                                                                          \
    if (DOPF) {                                                                \
      const __bf16* na_ = sm.kl.A + (NBUF) * 8192 + aoff;                      \
      const __bf16* nb_ = sm.kl.B + (NBUF) * 8192 + boff;                      \
      _Pragma("unroll") for (int i = 0; i < 4; ++i) {                          \
        NA[i] = *(const bf16x8*)(na_ + i * 512);                               \
        NB[i] = *(const bf16x8*)(nb_ + i * 512);                               \
      }                                                                        \
    }                                                                          \
    __builtin_amdgcn_s_setprio(1);                                             \
    _Pragma("unroll") for (int mi = 0; mi < 4; ++mi)                           \
      _Pragma("unroll") for (int ni = 0; ni < 4; ++ni)                         \
        acc[mi][ni] = __builtin_amdgcn_mfma_f32_16x16x32_bf16(                 \
            CA[mi], CB[ni], acc[mi][ni], 0, 0, 0);                             \
    _Pragma("unroll") for (int mi = 0; mi < 4; ++mi)                           \
      _Pragma("unroll") for (int ni = 0; ni < 4; ++ni)                         \
        acc[mi + 4][ni] = __builtin_amdgcn_mfma_f32_16x16x32_bf16(             \
            h1[mi], CB[ni], acc[mi + 4][ni], 0, 0, 0);                         \
    __builtin_amdgcn_s_setprio(0);                                             \
  }

template <int EPI>
__global__ __launch_bounds__(512, 2) void gemm256(const __bf16* __restrict__ A,
                                                  const __bf16* __restrict__ B,
                                                  void* __restrict__ Cout,
                                                  const float* __restrict__ bias) {
    __shared__ union __align__(16) {
        struct { __bf16 A[3 * 8192]; __bf16 B[3 * 8192]; } kl;   // 96 KiB
        __bf16 st[128][264];                                      // 66 KiB epi
    } sm;

    const int tid  = threadIdx.x;
    const int wave = tid >> 6, lane = tid & 63;
    const int wm = wave >> 2, wn = wave & 3;        // 2 x 4 wave grid
    const int quad = lane >> 4, m = lane & 15;

    // bijective XCD swizzle
    const int wg = blockIdx.x;
    int mb, nb;
    if (EPI == 0) {           // 768 blocks = 8 xcd x (8 mb x 12 nb)
        const int local = wg >> 3;                   // 0..95
        mb = (wg & 7) * 8 + (local & 7);             // 0..63
        nb = local >> 3;                             // 0..11
    } else {                  // 256 blocks = 8 xcd x (4 mb x 8 nb)
        const int local = wg >> 3;                   // 0..31
        mb = local & 3;                              // 0..3
        nb = (wg & 7) * 8 + (local >> 2);            // 0..63
    }
    const int m0 = mb << 8, n0 = nb << 8;

    const __bf16* Ab = A + ((size_t)m0 << 10);
    const __bf16* Bb = B + ((size_t)n0 << 10);

    // per-thread constant fragment offsets (elements).
    // swizzle: phys_chunk = quad ^ ((row>>1)&3); row base mult of 16 =>
    // ((row>>1)&3) == ((lane>>1)&3) for row = base + (lane&15).
    const int pcs  = quad ^ ((lane >> 1) & 3);
    const int aoff = (wm * 128 + m) * 32 + pcs * 8;  // + mi*512
    const int boff = (wn * 64  + m) * 32 + pcs * 8;  // + ni*512

    f32x4 acc[8][4] = {};
    bf16x8 p0a[4], p0b[4], p1a[4], p1b[4];

    // prologue: tiles 0,1 -> bufs 0,1; read tile0 half0+B after stage0 lands
    stage_tile(Ab, Bb, sm.kl.A,        sm.kl.B,        0,  wave, lane);
    stage_tile(Ab, Bb, sm.kl.A + 8192, sm.kl.B + 8192, 32, wave, lane);
    WAITVM(4);
    __builtin_amdgcn_s_barrier();
    __builtin_amdgcn_sched_barrier(0);
    #pragma unroll
    for (int i = 0; i < 4; ++i) {
        p0a[i] = *(const bf16x8*)(sm.kl.A + aoff + i * 512);
        p0b[i] = *(const bf16x8*)(sm.kl.B + boff + i * 512);
    }

    for (int tt = 0; tt < 30; tt += 6) {
        GBODY(0, 1, tt + 0, 1, 1, p0a, p0b, p1a, p1b);
        GBODY(1, 2, tt + 1, 1, 1, p1a, p1b, p0a, p0b);
        GBODY(2, 0, tt + 2, 1, 1, p0a, p0b, p1a, p1b);
        GBODY(0, 1, tt + 3, 1, 1, p1a, p1b, p0a, p0b);
        GBODY(1, 2, tt + 4, 1, 1, p0a, p0b, p1a, p1b);
        GBODY(2, 0, tt + 5, 1, 1, p1a, p1b, p0a, p0b);
    }
    GBODY(0, 1, 30, 0, 1, p0a, p0b, p1a, p1b);   // no more staging
    GBODY(1, 0, 31, 0, 0, p1a, p1b, p0a, p0b);   // last tile

    if (EPI == 0) {
        // ---- stage 128-row halves through LDS, coalesced bf16x8 stores
        __syncthreads();
        __bf16* Y = (__bf16*)Cout;
        #pragma unroll
        for (int h = 0; h < 2; ++h) {
            if (wm == h) {
                #pragma unroll
                for (int mi = 0; mi < 8; ++mi)
                    #pragma unroll
                    for (int ni = 0; ni < 4; ++ni) {
                        const int r = mi * 16 + quad * 4;
                        const int c = wn * 64 + ni * 16 + m;
                        #pragma unroll
                        for (int j = 0; j < 4; ++j)
                            sm.st[r + j][c] = to_bf(acc[mi][ni][j]);
                    }
            }
            __syncthreads();
            #pragma unroll
            for (int i = 0; i < 8; ++i) {
                const int cid = i * 512 + tid;
                const int r = cid >> 5, ch = (cid & 31) * 8;
                *(bf16x8*)(Y + (size_t)(m0 + h * 128 + r) * 3072 + n0 + ch) =
                    *(const bf16x8*)&sm.st[r][ch];
            }
            __syncthreads();
        }
    } else {
        // direct scatter of C[m=oc][n=b*256+s] into out[b][oc][s] (+bias)
        float* outp = (float*)Cout;
        const int cl = lane & 15, rq = lane >> 4;
        const int rbase = m0 + wm * 128 + rq * 4;
        const int nbase = n0 + wn * 64 + cl;
        #pragma unroll
        for (int mi = 0; mi < 8; ++mi) {
            float bia[4];
            #pragma unroll
            for (int j = 0; j < 4; ++j) bia[j] = bias[rbase + mi * 16 + j];
            #pragma unroll
            for (int ni = 0; ni < 4; ++ni) {
                const int nn = nbase + ni * 16;
                const size_t base = ((size_t)(nn >> 8) << 18) + (nn & 255);
                #pragma unroll
                for (int j = 0; j < 4; ++j) {
                    const int oc = rbase + mi * 16 + j;
                    outp[base + ((size_t)oc << 8)] = acc[mi][ni][j] + bia[j];
                }
            }
        }
    }
}

// ---------------------------------------------------------------------------
// attn_mfma: 16 waves/block, one token per wave (16 consecutive n of one batch).
// o = (softmax_d(rope(q))*scale · softmax_h(rope(k))^T) · v   via MFMA.
// ---------------------------------------------------------------------------
__global__ __launch_bounds__(1024) void attn_mfma(const __bf16* __restrict__ Y,
                                                  __bf16* __restrict__ Ot) {
    __shared__ union __align__(16) {
        __bf16  v[16][1024];      // per-wave v[16 h][64 e]
        ushort4 ost[256][16];     // [s][slot] row-strips (XOR-swizzled slots)
    } sm;

    const int tid  = threadIdx.x;
    const int wave = tid >> 6, lane = tid & 63;
    const int bb = blockIdx.x >> 4;
    const int n0 = (blockIdx.x & 15) * 16;
    const int n  = n0 + wave;
    const int quad = lane >> 4, m = lane & 15;
    const __bf16* Yt = Y + (size_t)(bb * 256 + n) * J3;

    #pragma unroll
    for (int p = 0; p < 2; ++p) {
        const int h = p * 8 + (lane >> 3), part = lane & 7;
        gload_lds16(Yt + h * 192 + 128 + part * 8, &sm.v[wave][p * 512]);
    }

    bf16x8 qb[2], kb[2];
    #pragma unroll
    for (int st = 0; st < 2; ++st) {
        qb[st] = *(const bf16x8*)(Yt + m * 192 +      st * 32 + quad * 8);
        kb[st] = *(const bf16x8*)(Yt + m * 192 + 64 + st * 32 + quad * 8);
    }
    float qf[16], kf[16];
    #pragma unroll
    for (int st = 0; st < 2; ++st)
        #pragma unroll
        for (int j = 0; j < 8; ++j) {
            qf[st * 8 + j] = (float)qb[st][j];
            kf[st * 8 + j] = (float)kb[st][j];
        }

    const float fn = (float)n;
    #pragma unroll
    for (int j = 0; j < 8; ++j) {
        const float d  = (float)(quad * 8 + j);
        const float th = fn * __expf(-0.28782313662425572f * d);  // n * 10000^(-d/32)
        const float sn = __sinf(th), cn = __cosf(th);
        float a0 = qf[j], a1 = qf[8 + j];
        qf[j]     = a0 * cn - a1 * sn;
        qf[8 + j] = a1 * cn + a0 * sn;
        float b0 = kf[j], b1 = kf[8 + j];
        kf[j]     = b0 * cn - b1 * sn;
        kf[8 + j] = b1 * cn + b0 * sn;
    }

    float qe[16], ls = 0.f;
    #pragma unroll
    for (int i = 0; i < 16; ++i) { qe[i] = __expf(qf[i]); ls += qe[i]; }
    ls += __shfl_xor(ls, 16);
    ls += __shfl_xor(ls, 32);
    const float qinv = 0.125f * __builtin_amdgcn_rcpf(ls);
    bf16x8 qbh[2];
    #pragma unroll
    for (int st = 0; st < 2; ++st)
        #pragma unroll
        for (int j = 0; j < 8; ++j) qbh[st][j] = to_bf(qe[st * 8 + j] * qinv);

    float ke[16], kc[16];
    #pragma unroll
    for (int i = 0; i < 16; ++i) { ke[i] = __expf(kf[i]); kc[i] = ke[i]; }
    #pragma unroll
    for (int msk = 1; msk <= 8; msk <<= 1)
        #pragma unroll
        for (int i = 0; i < 16; ++i) kc[i] += __shfl_xor(kc[i], msk);
    bf16x8 kbh[2];
    #pragma unroll
    for (int st = 0; st < 2; ++st)
        #pragma unroll
        for (int j = 0; j < 8; ++j)
            kbh[st][j] = to_bf(ke[st * 8 + j] * __builtin_amdgcn_rcpf(kc[st * 8 + j]));

    f32x4 Sp = {0.f, 0.f, 0.f, 0.f};
    Sp = __builtin_amdgcn_mfma_f32_16x16x32_bf16(kbh[0], qbh[0], Sp, 0, 0, 0);
    Sp = __builtin_amdgcn_mfma_f32_16x16x32_bf16(kbh[1], qbh[1], Sp, 0, 0, 0);

    __syncthreads();   // drain v DMA before LDS picks

    f32x4 o4[4];
#if __has_builtin(__builtin_amdgcn_mfma_f32_16x16x16f16)
    f16x4 af;
    #pragma unroll
    for (int r = 0; r < 4; ++r) af[r] = (_Float16)Sp[r];
    #pragma unroll
    for (int tile = 0; tile < 4; ++tile) {
        f16x4 bv;
        #pragma unroll
        for (int j = 0; j < 4; ++j)
            bv[j] = (_Float16)(float)sm.v[wave][(quad * 4 + j) * 64 + tile * 16 + m];
        f32x4 z = {0.f, 0.f, 0.f, 0.f};
        o4[tile] = __builtin_amdgcn_mfma_f32_16x16x16f16(af, bv, z, 0, 0, 0);
    }
#else
    bf16x8 a2;
    #pragma unroll
    for (int j = 0; j < 8; ++j) {
        int k = quad * 8 + j;
        int src = ((k & 15) >> 2) * 16 + m;
        float v = __shfl(Sp[k & 3], src, 64);
        a2[j] = (quad < 2) ? to_bf(v) : to_bf(0.f);
    }
    #pragma unroll
    for (int tile = 0; tile < 4; ++tile) {
        bf16x8 bv;
        #pragma unroll
        for (int j = 0; j < 8; ++j) {
            int k = quad * 8 + j;
            int kk = (k < 16) ? k : 0;
            bv[j] = sm.v[wave][kk * 64 + tile * 16 + m];
        }
        f32x4 z = {0.f, 0.f, 0.f, 0.f};
        o4[tile] = __builtin_amdgcn_mfma_f32_16x16x32_bf16(a2, bv, z, 0, 0, 0);
    }
#endif

    __syncthreads();   // v dead; reuse LDS as ost

    #pragma unroll
    for (int r = 0; r < 4; ++r) {
        const int s = m * 16 + quad * 4 + r;
        const int phys = wave ^ (quad * 4 + r) ^ m;
        ushort4 u;
        u.x = fbits(o4[0][r]); u.y = fbits(o4[1][r]);
        u.z = fbits(o4[2][r]); u.w = fbits(o4[3][r]);
        sm.ost[s][phys] = u;
    }
    __syncthreads();

    {
        const int row = tid >> 2;
        const int w0  = (tid & 3) * 4;
        ushort4 u4[4];
        #pragma unroll
        for (int j = 0; j < 4; ++j) {
            const int phys = (w0 + j) ^ (row & 15) ^ (row >> 4);
            u4[j] = sm.ost[row][phys];
        }
        __bf16* dst = Ot + (((size_t)(bb * 256 + row)) << 10) + n0 * 4 + w0 * 4;
        u16x8 a = {u4[0].x, u4[0].y, u4[0].z, u4[0].w, u4[1].x, u4[1].y, u4[1].z, u4[1].w};
        u16x8 b = {u4[2].x, u4[2].y, u4[2].z, u4[2].w, u4[3].x, u4[3].y, u4[3].z, u4[3].w};
        *(u16x8*)dst = a;
        *(u16x8*)(dst + 8) = b;
    }
}

// ---------------------------------------------------------------------------
extern "C" void kernel_launch(void* const* d_in, const int* in_sizes, int n_in,
                              void* d_out, int out_size, void* d_ws, size_t ws_size,
                              hipStream_t stream) {
    const float* x     = (const float*)d_in[0];
    const float* w_qkv = (const float*)d_in[1];
    const float* w_lin = (const float*)d_in[2];
    const float* b_lin = (const float*)d_in[3];
    float* out = (float*)d_out;

    char* ws = (char*)d_ws;
    __bf16* Y    = (__bf16*)ws;                               // 96 MiB [16384,3072]
    __bf16* XtOt = (__bf16*)(ws + (size_t)100663296);         // 32 MiB [16384,1024] (Xt then Ot)
    __bf16* Wqb  = (__bf16*)(ws + (size_t)134217728);         // 6 MiB  [3072,1024]
    __bf16* Wlb  = (__bf16*)(ws + (size_t)140509184);         // 2 MiB  [1024,1024]

    cvt_w<<<4096, 256, 0, stream>>>(w_qkv, Wqb, w_lin, Wlb);
    xpose_x<<<dim3(8, 32, 64), 256, 0, stream>>>(x, XtOt);

    gemm256<0><<<768, 512, 0, stream>>>(XtOt, Wqb, (void*)Y, nullptr);
    attn_mfma<<<1024, 1024, 0, stream>>>(Y, XtOt);            // Xt dead; reuse as Ot
    gemm256<1><<<256, 512, 0, stream>>>(Wlb, XtOt, (void*)out, b_lin);
}